// Round 16
// baseline (171.417 us; speedup 1.0000x reference)
//
#include <hip/hip_runtime.h>

#define NELEM 1048576   // N, power of two
#define BROWS 16        // B

typedef float fvec4 __attribute__((ext_vector_type(4)));

__global__ __launch_bounds__(256)
void weno_z_kernel(const float* __restrict__ x, float* __restrict__ out) {
    const int b = blockIdx.y;
    const int i = (blockIdx.x * 256 + threadIdx.x) * 16;  // first of 16 owned outputs
    const float* __restrict__ row  = x   + (size_t)b * NELEM;
    float* __restrict__       orow = out + (size_t)b * NELEM;

    // window w[j] = x[i-4+j], j=0..23 ; outputs i+k use w[k+1 .. k+5], k=0..15
    float w[24];
    if (i >= 4 && i <= NELEM - 24) {
        #pragma unroll
        for (int c = 0; c < 6; ++c) {
            const fvec4 v = *reinterpret_cast<const fvec4*>(row + i - 4 + 4 * c);
            w[4*c+0] = v.x; w[4*c+1] = v.y; w[4*c+2] = v.z; w[4*c+3] = v.w;
        }
    } else {
        // only first (i==0) and last (i==N-16) thread per row take this path
        #pragma unroll
        for (int j = 0; j < 24; ++j)
            w[j] = row[(i - 4 + j) & (NELEM - 1)];
    }

    #pragma unroll
    for (int g = 0; g < 4; ++g) {   // 4 groups of 4 outputs; store per group
        float res[4];
        #pragma unroll
        for (int q = 0; q < 4; ++q) {
            const int k = 4 * g + q;
            const float s0 = w[k+1], s1 = w[k+2], s2 = w[k+3], s3 = w[k+4], s4 = w[k+5];

            // a = S · s
            const float a0 = s0 - 2.f*s1 + s2;
            const float a1 = s0 - 4.f*s1 + 3.f*s2;
            const float a2 = s1 - 2.f*s2 + s3;
            const float a3 = s1 - s3;
            const float a4 = s2 - 2.f*s3 + s4;
            const float a5 = 3.f*s2 - 4.f*s3 + s4;

            const float c1312 = 13.f / 12.f;
            const float IS0 = c1312*a0*a0 + 0.25f*a1*a1;
            const float IS1 = c1312*a2*a2 + 0.25f*a3*a3;
            const float IS2 = c1312*a4*a4 + 0.25f*a5*a5;

            const float T5 = fabsf(IS2 - IS0);
            const float e0 = IS0 + 1e-13f;
            const float e1 = IS1 + 1e-13f;
            const float e2 = IS2 + 1e-13f;

            // W_c = d_c*(1 + T5/e_c) = d_c*(e_c+T5)/e_c; scale all by e0*e1*e2
            // (common positive factor cancels in normalization) -> no div.
            // Per-element magnitudes stay in fp32 normal range (the old 8-way
            // prefix product overflowed; per-element rcp has no blowout).
            const float w0 = 0.1f * (e0 + T5) * (e1 * e2);
            const float w1 = 0.6f * (e1 + T5) * (e0 * e2);
            const float w2 = 0.3f * (e2 + T5) * (e0 * e1);

            // P = L · s  (1/6 folded in)
            const float P0 = ( 2.f*s0 - 7.f*s1 + 11.f*s2) * (1.f/6.f);
            const float P1 = (-1.f*s1 + 5.f*s2 +  2.f*s3) * (1.f/6.f);
            const float P2 = ( 2.f*s2 + 5.f*s3 -  1.f*s4) * (1.f/6.f);

            const float num = w0*P0 + w1*P1 + w2*P2;
            const float den = w0 + w1 + w2;

            // hardware rcp (~1 ulp on normals; bf16-compare threshold is 9e-2,
            // current absmax 1.6e-2 is quantization-dominated -> NR dropped)
            res[q] = num * __builtin_amdgcn_rcpf(den);
        }
        fvec4 o;
        o.x = res[0]; o.y = res[1]; o.z = res[2]; o.w = res[3];
        __builtin_nontemporal_store(o, reinterpret_cast<fvec4*>(orow + i + 4 * g));
    }
}

extern "C" void kernel_launch(void* const* d_in, const int* in_sizes, int n_in,
                              void* d_out, int out_size, void* d_ws, size_t ws_size,
                              hipStream_t stream) {
    const float* x = (const float*)d_in[0];
    float* out = (float*)d_out;

    const int threads = 256;
    const int blocks_x = NELEM / (threads * 16);   // 256
    dim3 grid(blocks_x, BROWS, 1);
    weno_z_kernel<<<grid, threads, 0, stream>>>(x, out);
}

// Round 18
// 108.213 us; speedup vs baseline: 1.5841x; 1.5841x over previous
//
#include <hip/hip_runtime.h>

#define NELEM 1048576   // N, power of two
#define BROWS 16        // B

typedef float fvec4 __attribute__((ext_vector_type(4)));

__global__ __launch_bounds__(256)
void weno_z_kernel(const float* __restrict__ x, float* __restrict__ out) {
    const int b = blockIdx.y;
    const int i = (blockIdx.x * 256 + threadIdx.x) * 8;   // first of 8 owned outputs
    const float* __restrict__ row  = x   + (size_t)b * NELEM;
    float* __restrict__       orow = out + (size_t)b * NELEM;

    // window w[j] = x[i-4+j], j=0..15 ; outputs i+k use w[k+1 .. k+5]
    // 8 outputs/thread = 32 B/lane store footprint; lanes at 32-B stride and
    // the two 16-B stores issued back-to-back -> full 64-B line coverage.
    // (16 outputs/thread put lanes at 64-B stride -> partial-line nt stores
    //  -> WRITE_SIZE 180 MB vs 64 MB ideal, kernel 100 us. Measured r16.)
    float w[16];
    if (i >= 4 && i <= NELEM - 16) {
        const fvec4 v0 = *reinterpret_cast<const fvec4*>(row + i - 4);
        const fvec4 v1 = *reinterpret_cast<const fvec4*>(row + i);
        const fvec4 v2 = *reinterpret_cast<const fvec4*>(row + i + 4);
        const fvec4 v3 = *reinterpret_cast<const fvec4*>(row + i + 8);
        w[0]=v0.x; w[1]=v0.y; w[2]=v0.z; w[3]=v0.w;
        w[4]=v1.x; w[5]=v1.y; w[6]=v1.z; w[7]=v1.w;
        w[8]=v2.x; w[9]=v2.y; w[10]=v2.z; w[11]=v2.w;
        w[12]=v3.x; w[13]=v3.y; w[14]=v3.z; w[15]=v3.w;
    } else {
        // only first (i==0) and last (i==N-8) thread per row take this path
        #pragma unroll
        for (int j = 0; j < 16; ++j)
            w[j] = row[(i - 4 + j) & (NELEM - 1)];
    }

    float res[8];
    #pragma unroll
    for (int k = 0; k < 8; ++k) {
        const float s0 = w[k+1], s1 = w[k+2], s2 = w[k+3], s3 = w[k+4], s4 = w[k+5];

        // a = S · s
        const float a0 = s0 - 2.f*s1 + s2;
        const float a1 = s0 - 4.f*s1 + 3.f*s2;
        const float a2 = s1 - 2.f*s2 + s3;
        const float a3 = s1 - s3;
        const float a4 = s2 - 2.f*s3 + s4;
        const float a5 = 3.f*s2 - 4.f*s3 + s4;

        const float c1312 = 13.f / 12.f;
        const float IS0 = c1312*a0*a0 + 0.25f*a1*a1;
        const float IS1 = c1312*a2*a2 + 0.25f*a3*a3;
        const float IS2 = c1312*a4*a4 + 0.25f*a5*a5;

        const float T5 = fabsf(IS2 - IS0);
        const float e0 = IS0 + 1e-13f;
        const float e1 = IS1 + 1e-13f;
        const float e2 = IS2 + 1e-13f;

        // W_c = d_c*(1 + T5/e_c) = d_c*(e_c+T5)/e_c; scale all by e0*e1*e2
        // (common positive factor cancels in normalization) -> no div here.
        // Per-element magnitudes stay in fp32 normal range (the old 8-way
        // prefix product overflowed to inf -> NaN; per-element rcp doesn't).
        const float w0 = 0.1f * (e0 + T5) * (e1 * e2);
        const float w1 = 0.6f * (e1 + T5) * (e0 * e2);
        const float w2 = 0.3f * (e2 + T5) * (e0 * e1);

        // P = L · s  (1/6 folded in)
        const float P0 = ( 2.f*s0 - 7.f*s1 + 11.f*s2) * (1.f/6.f);
        const float P1 = (-1.f*s1 + 5.f*s2 +  2.f*s3) * (1.f/6.f);
        const float P2 = ( 2.f*s2 + 5.f*s3 -  1.f*s4) * (1.f/6.f);

        const float num = w0*P0 + w1*P1 + w2*P2;
        const float den = w0 + w1 + w2;

        // hardware rcp (~1 ulp on normals; bf16-compare threshold is 9e-2,
        // absmax 1.6e-2 is quantization-dominated -> NR step not needed)
        res[k] = num * __builtin_amdgcn_rcpf(den);
    }

    fvec4 o0, o1;
    o0.x = res[0]; o0.y = res[1]; o0.z = res[2]; o0.w = res[3];
    o1.x = res[4]; o1.y = res[5]; o1.z = res[6]; o1.w = res[7];
    __builtin_nontemporal_store(o0, reinterpret_cast<fvec4*>(orow + i));
    __builtin_nontemporal_store(o1, reinterpret_cast<fvec4*>(orow + i + 4));
}

extern "C" void kernel_launch(void* const* d_in, const int* in_sizes, int n_in,
                              void* d_out, int out_size, void* d_ws, size_t ws_size,
                              hipStream_t stream) {
    const float* x = (const float*)d_in[0];
    float* out = (float*)d_out;

    const int threads = 256;
    const int blocks_x = NELEM / (threads * 8);   // 512
    dim3 grid(blocks_x, BROWS, 1);
    weno_z_kernel<<<grid, threads, 0, stream>>>(x, out);
}